// Round 8
// baseline (191.621 us; speedup 1.0000x reference)
//
#include <hip/hip_runtime.h>

// VQ-VAE quantization, round 14: epilogue ILP restructure.
// Round-7: nt streams neutral; epilogue still 44us @ 2.0TB/s while the
// harness memset streams 6.1TB/s on the same chip. Smoking gun: VGPR=12 ->
// compiler emitted a rolled loop with one fully-dependent chain per
// iteration (fidx load -> cbk gather -> store), zero overlap = latency-bound.
// Fix: trip counts are compile-time (grid 2048x256 -> exactly 4 iters/loop);
// fully unroll, batch loads by stage (8 code lookups, then 4 z nt-loads +
// 8 cbk gathers all in flight, then stores). Wave = one 1KB row per iter ->
// gathers stay perfectly coalesced.
// N=32768 rows (D=256), K=1024 codes.
// dist = ||e_k||^2 - 2 z.e_k  (||z||^2 dropped: argmin-invariant)

#define N_ROWS 32768
#define K_CODES 1024
#define D_DIM 256
#define M_ELEMS 8388608   // N_ROWS * D_DIM

#define TM 128
#define TN 128
#define BK 64
#define TAU 0.25f
#define TAU_MARGIN 0.07f  // covers 10-bit key truncation (<=0.0625)
#define CAP 8192
#define RPB 8             // cleanup rows per block (16 spills: VGPR cliff)
#define SPLIT 4           // cleanup code chunks (codes per block = 1024/SPLIT)

typedef __attribute__((ext_vector_type(8))) _Float16 half8;
typedef __attribute__((ext_vector_type(4))) _Float16 half4;
typedef __attribute__((ext_vector_type(4))) float f32x4;
typedef __attribute__((ext_vector_type(4), aligned(4))) float f4u;

__device__ inline void async16(const void* g, void* l) {
    __builtin_amdgcn_global_load_lds(
        (const __attribute__((address_space(1))) unsigned int*)g,
        (__attribute__((address_space(3))) unsigned int*)l, 16, 0, 0);
}

__device__ inline unsigned umin2(unsigned a, unsigned b) { return a < b ? a : b; }
__device__ inline unsigned umax2(unsigned a, unsigned b) { return a > b ? a : b; }

// float -> order-preserving u32 (strictly monotone over all finite floats)
__device__ inline unsigned ford(float f) {
    unsigned x = __float_as_uint(f);
    return x ^ ((unsigned)((int)x >> 31) | 0x80000000u);
}
// decode a key (code bits zeroed first); result <= true dist, err < 1024 ulp
__device__ inline float fdec(unsigned u) {
    unsigned b = u & 0xFFFFFC00u;
    b = (b & 0x80000000u) ? (b ^ 0x80000000u) : ~b;
    return __uint_as_float(b);
}

// final code for a row: approx winner, or cleanup's exact winner on sentinel
__device__ inline int final_code(const int* __restrict__ fidx,
                                 const unsigned long long* __restrict__ ck,
                                 int row) {
    int f = fidx[row];
    return (f >= 0) ? f : (int)(ck[row] & (unsigned long long)(K_CODES - 1));
}

// ---------------- fused prep: z->f16 | codebook f16 + fp32 transpose | norms ----------------
__global__ __launch_bounds__(256) void prep_kernel(
    const float* __restrict__ z, const float* __restrict__ cbk,
    _Float16* __restrict__ zh, _Float16* __restrict__ eh,
    float* __restrict__ cbkT, float* __restrict__ norms,
    int* __restrict__ count, float* __restrict__ out)
{
    __shared__ float tile[32][33];
    const int b = blockIdx.x;
    const int tid = threadIdx.x;

    if (b < 1024) {
        if (b == 0 && tid == 0) { *count = 0; out[M_ELEMS] = 0.f; }
        const int n4 = M_ELEMS / 4;
        const int stride = 1024 * 256;
        for (int i = b * 256 + tid; i < n4; i += stride) {
            float4 v = *(const float4*)(z + (size_t)i * 4);
            half4 h = {(_Float16)v.x, (_Float16)v.y, (_Float16)v.z, (_Float16)v.w};
            *(half4*)(zh + (size_t)i * 4) = h;
        }
    } else if (b < 1280) {
        int b2 = b - 1024;
        int bk = b2 & 31;                 // code block
        int bd = b2 >> 5;                 // dim block (0..7)
        int r  = tid >> 3;                // 0..31
        int c4 = (tid & 7) * 4;           // 0,4,..,28
        int k = bk * 32 + r;
        int d = bd * 32 + c4;
        float4 v = *(const float4*)(cbk + (size_t)k * D_DIM + d);
        half4 h = {(_Float16)v.x, (_Float16)v.y, (_Float16)v.z, (_Float16)v.w};
        *(half4*)(eh + (size_t)k * D_DIM + d) = h;
        tile[r][c4 + 0] = v.x; tile[r][c4 + 1] = v.y;
        tile[r][c4 + 2] = v.z; tile[r][c4 + 3] = v.w;
        __syncthreads();
        float4 o = {tile[c4 + 0][r], tile[c4 + 1][r], tile[c4 + 2][r], tile[c4 + 3][r]};
        *(float4*)(cbkT + (size_t)(bd * 32 + r) * K_CODES + bk * 32 + c4) = o;
    } else {
        int b2 = b - 1280;
        int wave = tid >> 6;
        int lane = tid & 63;
        int code = b2 * 4 + wave;         // 256 blocks * 4 = 1024 codes
        const float4 v = *(const float4*)(cbk + (size_t)code * D_DIM + lane * 4);
        float s = v.x * v.x + v.y * v.y + v.z * v.z + v.w * v.w;
        #pragma unroll
        for (int off = 32; off; off >>= 1) s += __shfl_down(s, off);
        if (lane == 0) norms[code] = s;
    }
}

// ---------------- main: f16 MFMA, global_load_lds, XOR-swizzled LDS ----------------
// XCD-chunked swizzle: the 8 col-blocks sharing a zh row-panel land on the
// SAME XCD -> panel L2-resident (verified: FETCH 66MB -> 10.4MB).
// Epilogue: packed-u32 top-2.
__global__ __launch_bounds__(256, 4) void vq_main_f16(
    const _Float16* __restrict__ zh, const _Float16* __restrict__ eh,
    const float* __restrict__ norms,
    unsigned* __restrict__ pval, unsigned* __restrict__ pval2)
{
    __shared__ __align__(16) _Float16 Ah[TM * BK];
    __shared__ __align__(16) _Float16 Bh[TN * BK];

    const int tid  = threadIdx.x;
    const int wid  = (blockIdx.x & 7) * 256 + (blockIdx.x >> 3);  // grid=2048, %8==0: bijective
    const int cbl  = wid & 7;
    const int rb   = wid >> 3;
    const int rbase = rb * TM;
    const int cbase = cbl * TN;

    const int w    = tid >> 6;
    const int lane = tid & 63;
    const int quad = lane >> 4;
    const int ml   = lane & 15;
    const int wrow = (w >> 1) * 64;
    const int wcol = (w & 1) * 64;

    f32x4 acc[4][4];
    #pragma unroll
    for (int i = 0; i < 4; ++i)
        #pragma unroll
        for (int j = 0; j < 4; ++j)
            acc[i][j] = (f32x4){0.f, 0.f, 0.f, 0.f};

    for (int dc = 0; dc < D_DIM / BK; ++dc) {   // 4 iterations
        // LDS slot (row,seg) holds global k-chunk seg^(row&7): XOR swizzle on
        // the SOURCE address (global_load_lds dest must stay lane-linear).
        #pragma unroll
        for (int q = 0; q < 4; ++q) {
            int cc  = q * 256 + tid;        // 0..1023
            int row = cc >> 3;
            int seg = cc & 7;
            int sg  = seg ^ (row & 7);
            async16(zh + (size_t)(rbase + row) * D_DIM + dc * BK + sg * 8, &Ah[cc * 8]);
            async16(eh + (size_t)(cbase + row) * D_DIM + dc * BK + sg * 8, &Bh[cc * 8]);
        }
        __syncthreads();

        half8 a[4][2];
        #pragma unroll
        for (int i = 0; i < 4; ++i) {
            int r = wrow + i * 16 + ml;
            #pragma unroll
            for (int kc = 0; kc < 2; ++kc)
                a[i][kc] = *(const half8*)&Ah[r * BK + (((kc << 2) + quad) ^ (r & 7)) * 8];
        }
        #pragma unroll
        for (int j = 0; j < 4; ++j) {
            int c = wcol + j * 16 + ml;
            #pragma unroll
            for (int kc = 0; kc < 2; ++kc) {
                half8 b = *(const half8*)&Bh[c * BK + (((kc << 2) + quad) ^ (c & 7)) * 8];
                #pragma unroll
                for (int i = 0; i < 4; ++i)
                    acc[i][j] = __builtin_amdgcn_mfma_f32_16x16x32_f16(a[i][kc], b, acc[i][j], 0, 0, 0);
            }
        }
        __syncthreads();
    }

    // ------- per-row top-2 over this block's 128 codes (packed u32 keys) -------
    float nrm[4];
    unsigned codej[4];
    #pragma unroll
    for (int j = 0; j < 4; ++j) {
        codej[j] = (unsigned)(cbase + wcol + j * 16 + ml);   // global code, 10 bits
        nrm[j]   = norms[codej[j]];
    }

    unsigned* pm1s = (unsigned*)Ah;                    // [128][2] overlays
    unsigned* pm2s = (unsigned*)&Ah[TM * BK / 2];

    #pragma unroll
    for (int i = 0; i < 4; ++i) {
        #pragma unroll
        for (int r = 0; r < 4; ++r) {
            unsigned m1 = 0xFFFFFFFFu, m2 = 0xFFFFFFFFu;
            #pragma unroll
            for (int j = 0; j < 4; ++j) {
                float dist = fmaf(-2.f, acc[i][j][r], nrm[j]);
                unsigned key = (ford(dist) & 0xFFFFFC00u) | codej[j];
                m2 = umin2(m2, umax2(m1, key));
                m1 = umin2(m1, key);
            }
            #pragma unroll
            for (int off = 1; off < 16; off <<= 1) {
                unsigned o1 = (unsigned)__shfl_xor((int)m1, off);
                unsigned o2 = (unsigned)__shfl_xor((int)m2, off);
                unsigned lo = umin2(m1, o1);
                unsigned hi = umax2(m1, o1);
                m1 = lo;
                m2 = umin2(hi, umin2(m2, o2));
            }
            if (ml == 0) {
                int rl = wrow + i * 16 + quad * 4 + r;
                pm1s[rl * 2 + (w & 1)] = m1;
                pm2s[rl * 2 + (w & 1)] = m2;
            }
        }
    }
    __syncthreads();

    if (tid < TM) {
        unsigned a1 = pm1s[tid * 2 + 0], b1 = pm1s[tid * 2 + 1];
        unsigned a2 = pm2s[tid * 2 + 0], b2 = pm2s[tid * 2 + 1];
        unsigned m1 = umin2(a1, b1);
        unsigned m2 = umin2(umax2(a1, b1), umin2(a2, b2));
        size_t o = (size_t)cbl * N_ROWS + rbase + tid;   // transposed: coalesced
        pval[o] = m1; pval2[o] = m2;
    }
}

// ---------------- merge 8 packed partials -> final idx; atomic compaction ----------------
// List ORDER is nondeterministic (atomic slots) but the listed SET is
// deterministic; listed rows get fidx=-1 + ck64 init, resolved by cleanup's
// deterministic atomicMin. Rows past CAP (never expected) keep approx code.
__global__ void merge_kernel(const unsigned* __restrict__ pval,
                             const unsigned* __restrict__ pval2,
                             int* __restrict__ fidx, int* __restrict__ count,
                             int* __restrict__ list,
                             unsigned long long* __restrict__ ck64) {
    int row = blockIdx.x * blockDim.x + threadIdx.x;
    unsigned m1 = pval[row], m2 = pval2[row];
    #pragma unroll
    for (int c = 1; c < 8; ++c) {
        size_t o = (size_t)c * N_ROWS + row;
        unsigned b1 = pval[o], b2 = pval2[o];
        unsigned lo = umin2(m1, b1);
        unsigned hi = umax2(m1, b1);
        m1 = lo;
        m2 = umin2(hi, umin2(m2, b2));
    }
    int code = (int)(m1 & (K_CODES - 1));
    float f1 = fdec(m1), f2 = fdec(m2);
    if (!(f2 - f1 >= TAU + TAU_MARGIN)) {    // NaN-safe + truncation-conservative
        int pos = atomicAdd(count, 1);       // wave-coalesced by compiler
        if (pos < CAP) {
            list[pos] = row;
            ck64[row] = 0xFFFFFFFFFFFFFFFFull;
            code = -1;                       // sentinel: resolve via ck64
        }
    }
    fidx[row] = code;
}

// ---------------- exact fp32 re-check: 8 rows x 256-code chunk per block ----------------
// grid = (CAP/RPB) * SPLIT. Each block reads a 256KB slice of cbkT; per-row
// winners combine across chunks via deterministic atomicMin on u64 keys.
__global__ __launch_bounds__(256) void cleanup_kernel(
    const float* __restrict__ z, const float* __restrict__ cbkT,
    const float* __restrict__ norms,
    const int* __restrict__ count_p, const int* __restrict__ list,
    unsigned long long* __restrict__ ck64)
{
    int count = *count_p;
    if (count < 0) count = 0; if (count > CAP) count = CAP;
    const int grp   = blockIdx.x / SPLIT;     // row-group
    const int chunk = blockIdx.x % SPLIT;     // code chunk
    int base = grp * RPB;
    if (base >= count) return;
    int nr = count - base; if (nr > RPB) nr = RPB;

    __shared__ float zs[RPB][256];                     // 8 KB
    __shared__ unsigned long long kv[RPB][256];        // 16 KB
    __shared__ int rows[RPB];
    const int tid  = threadIdx.x;
    const int code = chunk * (K_CODES / SPLIT) + tid;  // 1 code per thread

    if (tid < RPB) rows[tid] = list[base + (tid < nr ? tid : 0)] & (N_ROWS - 1);
    __syncthreads();
    #pragma unroll
    for (int r = 0; r < RPB; ++r)
        zs[r][tid] = (r < nr) ? z[(size_t)rows[r] * D_DIM + tid] : 0.f;
    __syncthreads();

    float acc[RPB];
    #pragma unroll
    for (int r = 0; r < RPB; ++r) acc[r] = 0.f;

    for (int d4 = 0; d4 < D_DIM / 4; ++d4) {
        float4 zv[RPB];
        #pragma unroll
        for (int r = 0; r < RPB; ++r) zv[r] = *(const float4*)&zs[r][d4 * 4];  // broadcast
        #pragma unroll
        for (int t = 0; t < 4; ++t) {
            float c = cbkT[(size_t)(d4 * 4 + t) * K_CODES + code];  // coalesced
            #pragma unroll
            for (int r = 0; r < RPB; ++r)
                acc[r] = fmaf(((const float*)&zv[r])[t], c, acc[r]);
        }
    }

    float nrm = norms[code];
    #pragma unroll
    for (int r = 0; r < RPB; ++r) {
        float dist = fmaf(-2.f, acc[r], nrm);
        kv[r][tid] = ((unsigned long long)ford(dist) << 32) | (unsigned)code;
    }
    __syncthreads();
    for (int s = 128; s; s >>= 1) {
        if (tid < s) {
            #pragma unroll
            for (int r = 0; r < RPB; ++r) {
                unsigned long long o = kv[r][tid + s];
                if (o < kv[r][tid]) kv[r][tid] = o;
            }
        }
        __syncthreads();
    }
    if (tid < nr) atomicMin(&ck64[rows[tid]], kv[tid][0]);
}

// ---------------- epilogue: fully-unrolled ILP, nt streams, atomic loss ----------------
// Grid fixed 2048x256 -> exactly 4 iters per phase (phase-2 last predicated).
// Stage-batched loads: 8 code lookups, then 4 z nt-loads + 8 cbk gathers all
// in flight, then stores. Replaces round-13's rolled loop (VGPR=12, fully
// serialized dependent chains, 2.0 TB/s).
__global__ __launch_bounds__(256) void epilogue_kernel(
    const float* __restrict__ z, const float* __restrict__ cbk,
    const int* __restrict__ fidx,
    const unsigned long long* __restrict__ ck64,
    float* __restrict__ out)
{
    __shared__ float wsum[4];
    const int gtid = blockIdx.x * blockDim.x + threadIdx.x;
    const int stride = 2048 * 256;
    float lsum = 0.f;

    // ---------- phase 1: z_e copy + loss (4 unconditional iterations) ----------
    // 64 consecutive i4 = one full 256-elem row -> code is wave-uniform,
    // z/cbk/out accesses are 1KB coalesced row streams.
    int code1[4];
    #pragma unroll
    for (int k = 0; k < 4; ++k)
        code1[k] = final_code(fidx, ck64, (gtid + k * stride) >> 6);
    f32x4 ze[4];
    #pragma unroll
    for (int k = 0; k < 4; ++k)
        ze[k] = __builtin_nontemporal_load(
            (const f32x4*)(z + (size_t)(gtid + k * stride) * 4));
    f32x4 zq[4];
    #pragma unroll
    for (int k = 0; k < 4; ++k) {
        int i4 = gtid + k * stride;
        zq[k] = *(const f32x4*)(cbk + (size_t)code1[k] * D_DIM + (i4 & 63) * 4);
    }
    #pragma unroll
    for (int k = 0; k < 4; ++k) {
        int i4 = gtid + k * stride;
        __builtin_nontemporal_store(ze[k], (f32x4*)(out + (size_t)i4 * 4));
        float dx = zq[k].x - ze[k].x, dy = zq[k].y - ze[k].y,
              dz = zq[k].z - ze[k].z, dw = zq[k].w - ze[k].w;
        lsum += dx * dx + dy * dy + dz * dz + dw * dw;
    }

    // ---------- phase 2: z_q scatter (4 iterations, last predicated) ----------
    float* out2 = out + M_ELEMS + 1;
    const int g2 = (M_ELEMS - 4) / 4;
    int code2[4], codeN[4], i0_[4];
    bool act[4];
    #pragma unroll
    for (int k = 0; k < 4; ++k) {
        int g = gtid + k * stride;
        act[k] = (g < g2);
        int gg = act[k] ? g : 0;
        i0_[k] = 3 + 4 * gg;
        int row = i0_[k] >> 8;
        int rown = (row + 1 < N_ROWS) ? row + 1 : row;
        code2[k] = final_code(fidx, ck64, row);
        codeN[k] = final_code(fidx, ck64, rown);   // only used when d0==255
    }
    f32x4 v[4];
    #pragma unroll
    for (int k = 0; k < 4; ++k) {
        int d0 = i0_[k] & 255;
        if (d0 <= D_DIM - 4) {
            f4u t = *(const f4u*)(cbk + (size_t)code2[k] * D_DIM + d0);
            v[k] = (f32x4){t.x, t.y, t.z, t.w};
        } else {            // d0==255: spans row boundary (lane 63 case)
            v[k][0] = cbk[(size_t)code2[k] * D_DIM + 255];
            v[k][1] = cbk[(size_t)codeN[k] * D_DIM + 0];
            v[k][2] = cbk[(size_t)codeN[k] * D_DIM + 1];
            v[k][3] = cbk[(size_t)codeN[k] * D_DIM + 2];
        }
    }
    #pragma unroll
    for (int k = 0; k < 4; ++k)
        if (act[k])
            __builtin_nontemporal_store(v[k], (f32x4*)(out2 + i0_[k]));  // 16B aligned

    if (gtid == 0) {
        int c0 = final_code(fidx, ck64, 0);
        int cl = final_code(fidx, ck64, N_ROWS - 1);
        out2[0] = cbk[(size_t)c0 * D_DIM + 0];
        out2[1] = cbk[(size_t)c0 * D_DIM + 1];
        out2[2] = cbk[(size_t)c0 * D_DIM + 2];
        out2[M_ELEMS - 1] = cbk[(size_t)cl * D_DIM + 255];
    }

    #pragma unroll
    for (int off = 32; off; off >>= 1) lsum += __shfl_down(lsum, off);
    if ((threadIdx.x & 63) == 0) wsum[threadIdx.x >> 6] = lsum;
    __syncthreads();
    if (threadIdx.x == 0)
        atomicAdd(out + M_ELEMS,
                  (wsum[0] + wsum[1] + wsum[2] + wsum[3]) * (2.0f / (float)M_ELEMS));
}

extern "C" void kernel_launch(void* const* d_in, const int* in_sizes, int n_in,
                              void* d_out, int out_size, void* d_ws, size_t ws_size,
                              hipStream_t stream) {
    const float* z   = (const float*)d_in[0];
    const float* cbk = (const float*)d_in[1];
    float* out = (float*)d_out;

    char* ws = (char*)d_ws;
    _Float16* zh  = (_Float16*)ws;                                   // 16 MB
    _Float16* eh  = zh + (size_t)M_ELEMS;                            // 512 KB
    float* cbkT   = (float*)(eh + (size_t)K_CODES * D_DIM);          // 1 MB
    float* norms  = cbkT + (size_t)K_CODES * D_DIM;                  // 4 KB
    unsigned* pval  = (unsigned*)(norms + K_CODES);                  // 1 MB
    unsigned* pval2 = pval + (size_t)N_ROWS * 8;                     // 1 MB
    int*   fidx   = (int*)(pval2 + (size_t)N_ROWS * 8);              // 128 KB
    int*   count  = fidx + N_ROWS;                                   // 64 B
    int*   list   = count + 16;                                      // 32 KB
    unsigned long long* ck64 = (unsigned long long*)(list + CAP);    // 256 KB

    prep_kernel<<<1536, 256, 0, stream>>>(z, cbk, zh, eh, cbkT, norms, count, out);
    vq_main_f16<<<(N_ROWS / TM) * (K_CODES / TN), 256, 0, stream>>>(
        zh, eh, norms, pval, pval2);
    merge_kernel<<<N_ROWS / 256, 256, 0, stream>>>(pval, pval2, fidx, count, list, ck64);
    cleanup_kernel<<<(CAP / RPB) * SPLIT, 256, 0, stream>>>(z, cbkT, norms, count, list, ck64);
    epilogue_kernel<<<2048, 256, 0, stream>>>(z, cbk, fidx, ck64, out);
}